// Round 14
// baseline (28.990 us; speedup 1.0000x reference)
//
#include <hip/hip_runtime.h>

#define OC 64
#define IC 32
#define KC 16

typedef __attribute__((ext_vector_type(8))) short bf16x8;
typedef __attribute__((ext_vector_type(16))) float f32x16;

__device__ inline unsigned short f2bf(float f) {
    unsigned u = __builtin_bit_cast(unsigned, f);
    unsigned r = (u + 0x7fffu + ((u >> 16) & 1u)) >> 16;
    return (unsigned short)r;
}

// ---------------------------------------------------------------------------
// Fused prep, 256-thr blocks, 2 work units each.  (r13 verbatim)
// blocks [0,720): xpose  -> bf16 xp[n][z=20][h=36][cg=4][w=36][c=8] (pad 2)
// blocks [720,1744): build_k -> bf16 Kb[og=2][cell=125][kc=4][o=32][c8=8]
// ---------------------------------------------------------------------------
__global__ __launch_bounds__(256) void prep(const float* __restrict__ x,
                                            const float* __restrict__ W,
                                            const float* __restrict__ P,
                                            short* __restrict__ xp,
                                            short* __restrict__ Kb) {
    __shared__ float sR[2][32][36];
    __shared__ float sWP[2][64];
    const int tid = threadIdx.x;
    const int u   = tid >> 7;
    const int ut  = tid & 127;
    const int b   = blockIdx.x;

    if (b < 720) {
        // ---------------- xpose (unit = one (n,z,h) row) ----------------
        const int ub = b * 2 + u;              // 0..1439
        const int n = ub / 720;
        const int rem = ub - n * 720;
        const int z = rem / 36;
        const int h = rem - z * 36;
        const int zr = z - 2, hr = h - 2;
        short* orow = xp + (size_t)((n * 20 + z) * 36 + h) * 1152;
        const bool edge = ((unsigned)zr >= 16u) || ((unsigned)hr >= 32u);

        if (!edge) {
            const float* xb = x + ((size_t)(n * 32) * 16 + zr) * 1024 + hr * 32;
            #pragma unroll
            for (int k = 0; k < 2; ++k) {      // 32c x 8 float4 along w
                const int id = ut + k * 128;
                const int c = id >> 3, w4 = id & 7;
                const float4 v = *reinterpret_cast<const float4*>(xb + c * 16384 + w4 * 4);
                float* dst = &sR[u][c][2 + w4 * 4];
                *reinterpret_cast<float2*>(dst)     = make_float2(v.x, v.y);
                *reinterpret_cast<float2*>(dst + 2) = make_float2(v.z, v.w);
            }
            {   // zero the w-pad columns 0,1,34,35
                const int c = ut >> 2, wz = ut & 3;
                const int w = (wz < 2) ? wz : 32 + wz;
                sR[u][c][w] = 0.f;
            }
        }
        __syncthreads();
        if (edge) {
            for (int idx = ut; idx < 144; idx += 128)
                *reinterpret_cast<float4*>(orow + idx * 8) =
                    make_float4(0.f, 0.f, 0.f, 0.f);
        } else {
            for (int idx = ut; idx < 144; idx += 128) {
                const int cg = idx / 36;
                const int w  = idx - cg * 36;
                bf16x8 pk;
                #pragma unroll
                for (int e = 0; e < 8; ++e) pk[e] = (short)f2bf(sR[u][cg * 8 + e][w]);
                *reinterpret_cast<bf16x8*>(orow + idx * 8) = pk;
            }
        }
    } else {
        // ---------------- build_k (unit = one (o,c) pair) ----------------
        const int pair = (b - 720) * 2 + u;    // 0..2047
        if (ut < 64)
            sWP[u][ut] = (ut < 16) ? W[pair * 16 + ut]
                                   : P[((ut >> 4) - 1) * 32768 + pair * 16 + (ut & 15)];
        __syncthreads();
        if (ut < 125) {
            const int cell = ut;
            const int l = cell / 25;
            const int j = (cell / 5) % 5;
            const int i = cell % 5;
            const float fl = (float)l, fj = (float)j, fi = (float)i;
            float acc = 0.f;
            #pragma unroll
            for (int k = 0; k < KC; ++k) {
                const float w  = sWP[u][k];
                const float p1 = sWP[u][16 + k] + 2.0f;  // depth
                const float p2 = sWP[u][32 + k] + 2.0f;  // width
                const float p3 = sWP[u][48 + k] + 2.0f;  // height
                const float f1 = floorf(p1), r1 = p1 - f1;
                const float f2 = floorf(p2), r2 = p2 - f2;
                const float f3 = floorf(p3), r3 = p3 - f3;
                const float wl = (fl == f1) ? (1.f - r1) : ((fl == f1 + 1.f) ? r1 : 0.f);
                const float wj = (fj == f3) ? (1.f - r3) : ((fj == f3 + 1.f) ? r3 : 0.f);
                const float wi = (fi == f2) ? (1.f - r2) : ((fi == f2 + 1.f) ? r2 : 0.f);
                acc += w * (wl * wj * wi);
            }
            const int o = pair >> 5, c = pair & 31;
            const int og = o >> 5;
            Kb[(size_t)(og * 125 + cell) * 1024 + (c >> 3) * 256 + (o & 31) * 8 + (c & 7)] =
                (short)f2bf(acc);
        }
    }
}

// ---------------------------------------------------------------------------
// Conv: implicit GEMM via mfma_f32_32x32x16_bf16, both operands LDS-staged.
// NEW vs r13: 2 blocks/CU for inter-block barrier decorrelation.
// Grid 512 = [n2][d16][hb8][og2]; block 256 thr = 4 waves (g2 x s2),
// wave tile = 32 o x 4 h-rows x 32 w (4 accs), c-half g, i-split s.
// LDS single-buffered: A plane-slab 51200 B + B 8-row window 18432 B
// = 69632 B -> 2 blocks/CU (139 KB), launch_bounds(256,2) -> VGPR<=256,
// 2 waves/SIMD from DIFFERENT blocks -> independent barrier groups.
// Per plane: barrier, STAGE A+B, barrier, 5 pipelined steps.
// ---------------------------------------------------------------------------
#define ASLOT 25600          // shorts: A buffer (51200 B)
#define BBASE 25600          // short offset of B buffer
#define BSLOT 9216           // shorts: B buffer, 8 rows (18432 B)

__global__ __launch_bounds__(256, 2) void conv_mfma(const short* __restrict__ Kb,
                                                    const short* __restrict__ xp,
                                                    const float* __restrict__ bias,
                                                    float* __restrict__ out) {
    // XCD-aware chunked swizzle (512 % 8 == 0 -> bijective)
    const int sw = (blockIdx.x & 7) * 64 + (blockIdx.x >> 3);
    const int og = sw & 1;
    const int hb = (sw >> 1) & 7;
    const int d  = (sw >> 4) & 15;
    const int n  = sw >> 8;
    const int h0 = hb * 4;

    __shared__ short sL[ASLOT + BSLOT];    // 69632 B

    const int tid  = threadIdx.x;
    const int wv   = tid >> 6;             // 0..3
    const int lane = tid & 63;
    const int wcol = lane & 31;
    const int hi   = lane >> 5;
    const int g    = wv & 1;               // c-half
    const int s    = (wv ^ (wv >> 1)) & 1; // i-split, (g,s) distinct per SIMD

    const short* srcA0 = Kb + (size_t)(og * 125) * 1024;
    const short* srcB0 = xp + ((size_t)(n * 20 + d) * 36 + h0) * 1152;

    const int aoff = wcol * 8 + (g * 2 + hi) * 256;
    const int boff = (g * 2 + hi) * 288 + wcol * 8;

    f32x16 ac0, ac1, ac2, ac3;
    #pragma unroll
    for (int e = 0; e < 16; ++e) { ac0[e] = 0.f; ac1[e] = 0.f; ac2[e] = 0.f; ac3[e] = 0.f; }

    bf16x8 Aq[2][3];   // [parity][ii]
    bf16x8 Bq[5][3];   // [row slot][ii]

#define STAGEA(L)                                                             \
    {                                                                         \
        const short* s_ = srcA0 + (size_t)(L) * 25600;                        \
        _Pragma("unroll")                                                     \
        for (int k_ = 0; k_ < 12; ++k_) {                                     \
            const int t_ = k_ * 256 + tid;                                    \
            __builtin_amdgcn_global_load_lds(                                 \
                (const __attribute__((address_space(1))) unsigned int*)(s_ + t_ * 8), \
                (__attribute__((address_space(3))) unsigned int*)(sL + t_ * 8), \
                16, 0, 0);                                                    \
        }                                                                     \
        if (tid < 128) {                                                      \
            const int t_ = 3072 + tid;                                        \
            __builtin_amdgcn_global_load_lds(                                 \
                (const __attribute__((address_space(1))) unsigned int*)(s_ + t_ * 8), \
                (__attribute__((address_space(3))) unsigned int*)(sL + t_ * 8), \
                16, 0, 0);                                                    \
        }                                                                     \
    }

#define STAGEB(L)                                                             \
    {                                                                         \
        const short* s_ = srcB0 + (size_t)(L) * 41472;                        \
        _Pragma("unroll")                                                     \
        for (int k_ = 0; k_ < 4; ++k_) {                                      \
            const int t_ = k_ * 256 + tid;                                    \
            __builtin_amdgcn_global_load_lds(                                 \
                (const __attribute__((address_space(1))) unsigned int*)(s_ + t_ * 8), \
                (__attribute__((address_space(3))) unsigned int*)(sL + BBASE + t_ * 8), \
                16, 0, 0);                                                    \
        }                                                                     \
        if (tid < 128) {                                                      \
            const int t_ = 1024 + tid;                                        \
            __builtin_amdgcn_global_load_lds(                                 \
                (const __attribute__((address_space(1))) unsigned int*)(s_ + t_ * 8), \
                (__attribute__((address_space(3))) unsigned int*)(sL + BBASE + t_ * 8), \
                16, 0, 0);                                                    \
        }                                                                     \
    }

#define LOADA(PAR, J, I0, NI)                                                 \
    {                                                                         \
        const short* pa_ = sL + ((J) * 5 + (I0)) * 1024 + aoff;               \
        _Pragma("unroll")                                                     \
        for (int ii = 0; ii < (NI); ++ii)                                     \
            Aq[PAR][ii] = *reinterpret_cast<const bf16x8*>(pa_ + ii * 1024);  \
    }

#define LOADB(SLOT, RW, I0, NI)                                               \
    {                                                                         \
        const short* pb_ = sL + BBASE + (RW) * 1152 + boff + (I0) * 8;        \
        _Pragma("unroll")                                                     \
        for (int ii = 0; ii < (NI); ++ii)                                     \
            Bq[SLOT][ii] = *reinterpret_cast<const bf16x8*>(pb_ + ii * 8);    \
    }

#define MFMA_STEP(J, NI)                                                      \
    {                                                                         \
        __builtin_amdgcn_s_setprio(1);                                        \
        _Pragma("unroll")                                                     \
        for (int ii = 0; ii < (NI); ++ii) {                                   \
            const bf16x8 a_ = Aq[(J) & 1][ii];                                \
            ac0 = __builtin_amdgcn_mfma_f32_32x32x16_bf16(a_, Bq[(J) % 5][ii], ac0, 0, 0, 0);       \
            ac1 = __builtin_amdgcn_mfma_f32_32x32x16_bf16(a_, Bq[((J) + 1) % 5][ii], ac1, 0, 0, 0); \
            ac2 = __builtin_amdgcn_mfma_f32_32x32x16_bf16(a_, Bq[((J) + 2) % 5][ii], ac2, 0, 0, 0); \
            ac3 = __builtin_amdgcn_mfma_f32_32x32x16_bf16(a_, Bq[((J) + 3) % 5][ii], ac3, 0, 0, 0); \
        }                                                                     \
        __builtin_amdgcn_s_setprio(0);                                        \
    }

#define MAIN(I0, NI)                                                          \
    {                                                                         \
        _Pragma("unroll")                                                     \
        for (int l = 0; l < 5; ++l) {                                         \
            if (l > 0) __syncthreads();    /* compute(l-1) done before overwrite */ \
            STAGEA(l); STAGEB(l);                                             \
            __syncthreads();               /* vmcnt(0) drain before barrier */ \
            LOADA(0, 0, I0, NI);                                              \
            LOADB(0, 0, I0, NI); LOADB(1, 1, I0, NI);                         \
            LOADB(2, 2, I0, NI); LOADB(3, 3, I0, NI);                         \
            _Pragma("unroll")                                                 \
            for (int j = 0; j < 5; ++j) {                                     \
                if (j < 4) {                                                  \
                    LOADA((j + 1) & 1, j + 1, I0, NI);                        \
                    LOADB((j + 4) % 5, j + 4, I0, NI);                        \
                }                                                             \
                MFMA_STEP(j, NI);                                             \
            }                                                                 \
        }                                                                     \
    }

    if (s == 0) { MAIN(0, 3) } else { MAIN(3, 2) }

#undef STAGEA
#undef STAGEB
#undef LOADA
#undef LOADB
#undef MFMA_STEP
#undef MAIN

    // ---- (g,s) 4-partial reduction via vectorized LDS exchange ----
    // layout: sF[cls4][r4][eg4][lane64][4 f32] = 65536 B, all b128 ops
    __syncthreads();
    float* sF = reinterpret_cast<float*>(sL);
    const int cls = g * 2 + s;
#define PWRITE(R, A)                                                          \
    {                                                                         \
        float* p_ = sF + (((cls * 4 + (R)) * 4) * 64 + lane) * 4;             \
        _Pragma("unroll")                                                     \
        for (int eg = 0; eg < 4; ++eg) {                                      \
            float4 v_ = make_float4(A[4 * eg], A[4 * eg + 1],                 \
                                    A[4 * eg + 2], A[4 * eg + 3]);            \
            *reinterpret_cast<float4*>(p_ + eg * 256) = v_;                   \
        }                                                                     \
    }
    PWRITE(0, ac0) PWRITE(1, ac1) PWRITE(2, ac2) PWRITE(3, ac3)
#undef PWRITE
    __syncthreads();

    // wave wv stores output row h0+wv (rR = wv)
    const int rR = wv;
    const int h = h0 + wv;
    #pragma unroll
    for (int eg = 0; eg < 4; ++eg) {
        float4 sv = make_float4(0.f, 0.f, 0.f, 0.f);
        #pragma unroll
        for (int c4 = 0; c4 < 4; ++c4) {
            const float4 t = *reinterpret_cast<const float4*>(
                sF + (((c4 * 4 + rR) * 4 + eg) * 64 + lane) * 4);
            sv.x += t.x; sv.y += t.y; sv.z += t.z; sv.w += t.w;
        }
        #pragma unroll
        for (int k = 0; k < 4; ++k) {
            const int e = eg * 4 + k;
            const int o = og * 32 + (e & 3) + 8 * (e >> 2) + 4 * hi;
            const float v = (k == 0) ? sv.x : (k == 1) ? sv.y : (k == 2) ? sv.z : sv.w;
            out[((size_t)(n * 64 + o) * 16 + d) * 1024 + h * 32 + wcol] = v + bias[o];
        }
    }
}

extern "C" void kernel_launch(void* const* d_in, const int* in_sizes, int n_in,
                              void* d_out, int out_size, void* d_ws, size_t ws_size,
                              hipStream_t stream) {
    const float* x    = (const float*)d_in[0];
    const float* W    = (const float*)d_in[1];
    const float* P    = (const float*)d_in[2];
    const float* bias = (const float*)d_in[3];
    float* outp = (float*)d_out;

    short* Kb = (short*)d_ws;                          // 2*125*1024*2 = 512000 B
    short* xp = (short*)((char*)d_ws + 524288);        // 2*20*36*1152*2 = 3317760 B

    prep<<<1744, 256, 0, stream>>>(x, W, P, xp, Kb);
    conv_mfma<<<512, 256, 0, stream>>>(Kb, xp, bias, outp);
}

// Round 15
// 25.567 us; speedup vs baseline: 1.1339x; 1.1339x over previous
//
#include <hip/hip_runtime.h>

#define OC 64
#define IC 32
#define KC 16

typedef __attribute__((ext_vector_type(8))) short bf16x8;
typedef __attribute__((ext_vector_type(16))) float f32x16;

__device__ inline unsigned short f2bf(float f) {
    unsigned u = __builtin_bit_cast(unsigned, f);
    unsigned r = (u + 0x7fffu + ((u >> 16) & 1u)) >> 16;
    return (unsigned short)r;
}

// ---------------------------------------------------------------------------
// Fused prep, 256-thr blocks, 2 work units each.
// blocks [0,720): xpose  -> bf16 xp[n][z=20][h=36][cg=4][w=36][c=8] (pad 2)
// blocks [720,1744): build_k -> bf16 Kb[og=2][cell=125][kc=4][o=32][c8=8]
// ---------------------------------------------------------------------------
__global__ __launch_bounds__(256) void prep(const float* __restrict__ x,
                                            const float* __restrict__ W,
                                            const float* __restrict__ P,
                                            short* __restrict__ xp,
                                            short* __restrict__ Kb) {
    __shared__ float sR[2][32][36];
    __shared__ float sWP[2][64];
    const int tid = threadIdx.x;
    const int u   = tid >> 7;
    const int ut  = tid & 127;
    const int b   = blockIdx.x;

    if (b < 720) {
        // ---------------- xpose (unit = one (n,z,h) row) ----------------
        const int ub = b * 2 + u;              // 0..1439
        const int n = ub / 720;
        const int rem = ub - n * 720;
        const int z = rem / 36;
        const int h = rem - z * 36;
        const int zr = z - 2, hr = h - 2;
        short* orow = xp + (size_t)((n * 20 + z) * 36 + h) * 1152;
        const bool edge = ((unsigned)zr >= 16u) || ((unsigned)hr >= 32u);

        if (!edge) {
            const float* xb = x + ((size_t)(n * 32) * 16 + zr) * 1024 + hr * 32;
            #pragma unroll
            for (int k = 0; k < 2; ++k) {      // 32c x 8 float4 along w
                const int id = ut + k * 128;
                const int c = id >> 3, w4 = id & 7;
                const float4 v = *reinterpret_cast<const float4*>(xb + c * 16384 + w4 * 4);
                float* dst = &sR[u][c][2 + w4 * 4];
                *reinterpret_cast<float2*>(dst)     = make_float2(v.x, v.y);
                *reinterpret_cast<float2*>(dst + 2) = make_float2(v.z, v.w);
            }
            {   // zero the w-pad columns 0,1,34,35
                const int c = ut >> 2, wz = ut & 3;
                const int w = (wz < 2) ? wz : 32 + wz;
                sR[u][c][w] = 0.f;
            }
        }
        __syncthreads();
        if (edge) {
            for (int idx = ut; idx < 144; idx += 128)
                *reinterpret_cast<float4*>(orow + idx * 8) =
                    make_float4(0.f, 0.f, 0.f, 0.f);
        } else {
            for (int idx = ut; idx < 144; idx += 128) {
                const int cg = idx / 36;
                const int w  = idx - cg * 36;
                bf16x8 pk;
                #pragma unroll
                for (int e = 0; e < 8; ++e) pk[e] = (short)f2bf(sR[u][cg * 8 + e][w]);
                *reinterpret_cast<bf16x8*>(orow + idx * 8) = pk;
            }
        }
    } else {
        // ---------------- build_k (unit = one (o,c) pair) ----------------
        const int pair = (b - 720) * 2 + u;    // 0..2047
        if (ut < 64)
            sWP[u][ut] = (ut < 16) ? W[pair * 16 + ut]
                                   : P[((ut >> 4) - 1) * 32768 + pair * 16 + (ut & 15)];
        __syncthreads();
        if (ut < 125) {
            const int cell = ut;
            const int l = cell / 25;
            const int j = (cell / 5) % 5;
            const int i = cell % 5;
            const float fl = (float)l, fj = (float)j, fi = (float)i;
            float acc = 0.f;
            #pragma unroll
            for (int k = 0; k < KC; ++k) {
                const float w  = sWP[u][k];
                const float p1 = sWP[u][16 + k] + 2.0f;  // depth
                const float p2 = sWP[u][32 + k] + 2.0f;  // width
                const float p3 = sWP[u][48 + k] + 2.0f;  // height
                const float f1 = floorf(p1), r1 = p1 - f1;
                const float f2 = floorf(p2), r2 = p2 - f2;
                const float f3 = floorf(p3), r3 = p3 - f3;
                const float wl = (fl == f1) ? (1.f - r1) : ((fl == f1 + 1.f) ? r1 : 0.f);
                const float wj = (fj == f3) ? (1.f - r3) : ((fj == f3 + 1.f) ? r3 : 0.f);
                const float wi = (fi == f2) ? (1.f - r2) : ((fi == f2 + 1.f) ? r2 : 0.f);
                acc += w * (wl * wj * wi);
            }
            const int o = pair >> 5, c = pair & 31;
            const int og = o >> 5;
            Kb[(size_t)(og * 125 + cell) * 1024 + (c >> 3) * 256 + (o & 31) * 8 + (c & 7)] =
                (short)f2bf(acc);
        }
    }
}

// ---------------------------------------------------------------------------
// Conv: implicit GEMM via mfma_f32_32x32x16_bf16, both operands LDS-staged.
// Grid 256 = [n2][d16][hb4][og2], 1 block/CU. Block 512 thr = 8 waves =
// (hp2 x g2 x s2). launch_bounds(512,2) -> 2 waves/SIMD guaranteed.
// STAGEB deferred to after step j=0 (spread VMEM issue); epilogue
// partial-exchange vectorized to b128 ([cls][hp][r][eg][lane][4f32]).
// ---------------------------------------------------------------------------
#define ASLOT 25600          // shorts per A buffer (51200 B)
#define BBASE 51200          // short offset of B buffers
#define BSLOT 13824          // shorts per B buffer (27648 B)

__global__ __launch_bounds__(512, 2) void conv_mfma(const short* __restrict__ Kb,
                                                    const short* __restrict__ xp,
                                                    const float* __restrict__ bias,
                                                    float* __restrict__ out) {
    // XCD-aware chunked swizzle (256 % 8 == 0 -> bijective)
    const int sw = (blockIdx.x & 7) * 32 + (blockIdx.x >> 3);
    const int og = sw & 1;
    const int hb = (sw >> 1) & 3;
    const int d  = (sw >> 3) & 15;
    const int n  = sw >> 7;
    const int h0 = hb * 8;

    __shared__ short sL[2 * ASLOT + 2 * BSLOT];   // 157696 B

    const int tid  = threadIdx.x;
    const int wv   = tid >> 6;             // 0..7
    const int lane = tid & 63;
    const int wcol = lane & 31;
    const int hi   = lane >> 5;
    const int hp   = wv >> 2;              // h-quad (4 rows)
    const int g    = (wv >> 1) & 1;        // c-half
    const int s    = (wv ^ (wv >> 2)) & 1; // i-split, SIMD-balanced

    const short* srcA0 = Kb + (size_t)(og * 125) * 1024;
    const short* srcB0 = xp + ((size_t)(n * 20 + d) * 36 + h0) * 1152;

    const int aoff = wcol * 8 + (g * 2 + hi) * 256;
    const int boff = (g * 2 + hi) * 288 + wcol * 8;
    const int rb   = 4 * hp;               // wave's base B row

    f32x16 ac0, ac1, ac2, ac3;
    #pragma unroll
    for (int e = 0; e < 16; ++e) { ac0[e] = 0.f; ac1[e] = 0.f; ac2[e] = 0.f; ac3[e] = 0.f; }

    bf16x8 Aq[2][3];   // [parity][ii]
    bf16x8 Bq[5][3];   // [row slot][ii]

#define STAGEA(L, BUF)                                                        \
    {                                                                         \
        const short* s_ = srcA0 + (size_t)(L) * 25600;                        \
        short* d_ = sL + (BUF) * ASLOT;                                       \
        _Pragma("unroll")                                                     \
        for (int k_ = 0; k_ < 6; ++k_) {                                      \
            const int t_ = k_ * 512 + tid;                                    \
            __builtin_amdgcn_global_load_lds(                                 \
                (const __attribute__((address_space(1))) unsigned int*)(s_ + t_ * 8), \
                (__attribute__((address_space(3))) unsigned int*)(d_ + t_ * 8), \
                16, 0, 0);                                                    \
        }                                                                     \
        if (tid < 128) {                                                      \
            const int t_ = 3072 + tid;                                        \
            __builtin_amdgcn_global_load_lds(                                 \
                (const __attribute__((address_space(1))) unsigned int*)(s_ + t_ * 8), \
                (__attribute__((address_space(3))) unsigned int*)(d_ + t_ * 8), \
                16, 0, 0);                                                    \
        }                                                                     \
    }

#define STAGEB(L, BUF)                                                        \
    {                                                                         \
        const short* s_ = srcB0 + (size_t)(L) * 41472;                        \
        short* d_ = sL + BBASE + (BUF) * BSLOT;                               \
        _Pragma("unroll")                                                     \
        for (int k_ = 0; k_ < 3; ++k_) {                                      \
            const int t_ = k_ * 512 + tid;                                    \
            __builtin_amdgcn_global_load_lds(                                 \
                (const __attribute__((address_space(1))) unsigned int*)(s_ + t_ * 8), \
                (__attribute__((address_space(3))) unsigned int*)(d_ + t_ * 8), \
                16, 0, 0);                                                    \
        }                                                                     \
        if (tid < 192) {                                                      \
            const int t_ = 1536 + tid;                                        \
            __builtin_amdgcn_global_load_lds(                                 \
                (const __attribute__((address_space(1))) unsigned int*)(s_ + t_ * 8), \
                (__attribute__((address_space(3))) unsigned int*)(d_ + t_ * 8), \
                16, 0, 0);                                                    \
        }                                                                     \
    }

#define LOADA(PAR, BUF, J, I0, NI)                                            \
    {                                                                         \
        const short* pa_ = sL + (BUF) * ASLOT + ((J) * 5 + (I0)) * 1024 + aoff; \
        _Pragma("unroll")                                                     \
        for (int ii = 0; ii < (NI); ++ii)                                     \
            Aq[PAR][ii] = *reinterpret_cast<const bf16x8*>(pa_ + ii * 1024);  \
    }

#define LOADB(SLOT, BUF, RW, I0, NI)                                          \
    {                                                                         \
        const short* pb_ = sL + BBASE + (BUF) * BSLOT + (rb + (RW)) * 1152 + boff + (I0) * 8; \
        _Pragma("unroll")                                                     \
        for (int ii = 0; ii < (NI); ++ii)                                     \
            Bq[SLOT][ii] = *reinterpret_cast<const bf16x8*>(pb_ + ii * 8);    \
    }

#define MFMA_STEP(J, NI)                                                      \
    {                                                                         \
        __builtin_amdgcn_s_setprio(1);                                        \
        _Pragma("unroll")                                                     \
        for (int ii = 0; ii < (NI); ++ii) {                                   \
            const bf16x8 a_ = Aq[(J) & 1][ii];                                \
            ac0 = __builtin_amdgcn_mfma_f32_32x32x16_bf16(a_, Bq[(J) % 5][ii], ac0, 0, 0, 0);       \
            ac1 = __builtin_amdgcn_mfma_f32_32x32x16_bf16(a_, Bq[((J) + 1) % 5][ii], ac1, 0, 0, 0); \
            ac2 = __builtin_amdgcn_mfma_f32_32x32x16_bf16(a_, Bq[((J) + 2) % 5][ii], ac2, 0, 0, 0); \
            ac3 = __builtin_amdgcn_mfma_f32_32x32x16_bf16(a_, Bq[((J) + 3) % 5][ii], ac3, 0, 0, 0); \
        }                                                                     \
        __builtin_amdgcn_s_setprio(0);                                        \
    }

#define MAIN(I0, NI)                                                          \
    {                                                                         \
        STAGEA(0, 0); STAGEB(0, 0);                                           \
        __syncthreads();                                                      \
        _Pragma("unroll")                                                     \
        for (int l = 0; l < 5; ++l) {                                         \
            const int buf = l & 1;                                            \
            if (l < 4) STAGEA(l + 1, buf ^ 1);                                \
            LOADA(0, buf, 0, I0, NI);                                         \
            LOADB(0, buf, 0, I0, NI);                                         \
            LOADB(1, buf, 1, I0, NI);                                         \
            LOADB(2, buf, 2, I0, NI);                                         \
            LOADB(3, buf, 3, I0, NI);                                         \
            _Pragma("unroll")                                                 \
            for (int j = 0; j < 5; ++j) {                                     \
                if (j < 4) {                                                  \
                    LOADA((j + 1) & 1, buf, j + 1, I0, NI);                   \
                    LOADB((j + 4) % 5, buf, j + 4, I0, NI);                   \
                }                                                             \
                MFMA_STEP(j, NI);                                             \
                if (j == 0 && l < 4) STAGEB(l + 1, buf ^ 1);                  \
            }                                                                 \
            if (l < 4) __syncthreads();                                       \
        }                                                                     \
    }

    if (s == 0) { MAIN(0, 3) } else { MAIN(3, 2) }

#undef STAGEA
#undef STAGEB
#undef LOADA
#undef LOADB
#undef MFMA_STEP
#undef MAIN

    // ---- (g,s) 4-partial reduction via vectorized LDS exchange ----
    // layout: sF[cls4][hp2][r4][eg4][lane64][4 f32] = 131072 B, all b128 ops
    __syncthreads();
    float* sF = reinterpret_cast<float*>(sL);
    const int cls = g * 2 + s;
#define PWRITE(R, A)                                                          \
    {                                                                         \
        float* p_ = sF + ((((cls * 2 + hp) * 4 + (R)) * 4) * 64 + lane) * 4;  \
        _Pragma("unroll")                                                     \
        for (int eg = 0; eg < 4; ++eg) {                                      \
            float4 v_ = make_float4(A[4 * eg], A[4 * eg + 1],                 \
                                    A[4 * eg + 2], A[4 * eg + 3]);            \
            *reinterpret_cast<float4*>(p_ + eg * 256) = v_;                   \
        }                                                                     \
    }
    PWRITE(0, ac0) PWRITE(1, ac1) PWRITE(2, ac2) PWRITE(3, ac3)
#undef PWRITE
    __syncthreads();

    // wave wv stores output row h0+wv (hpR=wv>>2, rR=wv&3)
    const int hpR = wv >> 2, rR = wv & 3;
    const int h = h0 + wv;
    #pragma unroll
    for (int eg = 0; eg < 4; ++eg) {
        float4 sv = make_float4(0.f, 0.f, 0.f, 0.f);
        #pragma unroll
        for (int c4 = 0; c4 < 4; ++c4) {
            const float4 t = *reinterpret_cast<const float4*>(
                sF + ((((c4 * 2 + hpR) * 4 + rR) * 4 + eg) * 64 + lane) * 4);
            sv.x += t.x; sv.y += t.y; sv.z += t.z; sv.w += t.w;
        }
        #pragma unroll
        for (int k = 0; k < 4; ++k) {
            const int e = eg * 4 + k;
            const int o = og * 32 + (e & 3) + 8 * (e >> 2) + 4 * hi;
            const float v = (k == 0) ? sv.x : (k == 1) ? sv.y : (k == 2) ? sv.z : sv.w;
            out[((size_t)(n * 64 + o) * 16 + d) * 1024 + h * 32 + wcol] = v + bias[o];
        }
    }
}

extern "C" void kernel_launch(void* const* d_in, const int* in_sizes, int n_in,
                              void* d_out, int out_size, void* d_ws, size_t ws_size,
                              hipStream_t stream) {
    const float* x    = (const float*)d_in[0];
    const float* W    = (const float*)d_in[1];
    const float* P    = (const float*)d_in[2];
    const float* bias = (const float*)d_in[3];
    float* outp = (float*)d_out;

    short* Kb = (short*)d_ws;                          // 2*125*1024*2 = 512000 B
    short* xp = (short*)((char*)d_ws + 524288);        // 2*20*36*1152*2 = 3317760 B

    prep<<<1744, 256, 0, stream>>>(x, W, P, xp, Kb);
    conv_mfma<<<256, 512, 0, stream>>>(Kb, xp, bias, outp);
}